// Round 6
// baseline (60098.621 us; speedup 1.0000x reference)
//
#include <hip/hip_runtime.h>

#define NBLK 256
#define NTHR 512
#define HDIM 512
#define TSTEPS 1024
#define WUP 512
#define WPL 786432   /* weight plane elems: 1536*512 */
#define HPL 524288   /* h plane elems per buffer: 1024*512 */

// LDS map
#define GH_P(p) ((p) * 24576)            /* [0, 49152): Whh2 dbuf */
#define GA_P(p) (49152 + (p) * 49152)    /* [49152, 147456): Wih2+Whh1 dbuf */
#define REDOFF 0                         /* k-split reduce scratch (reuses GH region) */
#define CCOFF 147456                     /* per-col constants, 2560 B */

typedef unsigned short u16;
typedef unsigned int u32;
typedef __bf16 bf16x8 __attribute__((ext_vector_type(8)));
typedef float f32x4 __attribute__((ext_vector_type(4)));
typedef int i32x4 __attribute__((ext_vector_type(4)));

typedef __attribute__((address_space(3))) void as3v;
typedef __attribute__((address_space(1))) const void as1cv;

__device__ __forceinline__ void gload16(const u16* g, char* l) {
  __builtin_amdgcn_global_load_lds((as1cv*)g, (as3v*)l, 16, 0, 0);
}
// coherent (L1/L2-bypass) 16B load: reads at the L3 coherence point, no cache inv
__device__ __forceinline__ i32x4 load_sc(const u16* p) {
  i32x4 r;
  asm volatile("global_load_dwordx4 %0, %1, off sc0 sc1" : "=v"(r) : "v"(p) : "memory");
  return r;
}

__device__ __forceinline__ u16 f2bf(float f) {
  u32 u = __float_as_uint(f);
  u += 0x7fffu + ((u >> 16) & 1u);   // RNE to bf16
  return (u16)(u >> 16);
}
__device__ __forceinline__ float bf2f(u16 s) { return __uint_as_float(((u32)s) << 16); }
__device__ __forceinline__ float sigm(float v) { return 1.f / (1.f + __expf(-v)); }
__device__ __forceinline__ float tanh_(float v) {
  float e = __expf(2.f * v);
  return 1.f - 2.f / (e + 1.f);
}
__device__ __forceinline__ f32x4 MFMA(bf16x8 a, bf16x8 b, f32x4 c) {
  return __builtin_amdgcn_mfma_f32_16x16x32_bf16(a, b, c, 0, 0, 0);
}

// ---- group barrier (R4-proven): release RMW (wbl2, no inv) + relaxed poll ----
__device__ __forceinline__ void g_arrive(int* gb) {
  __syncthreads();
  if (threadIdx.x == 0) {
    int old = __hip_atomic_fetch_add(gb, 1, __ATOMIC_RELEASE, __HIP_MEMORY_SCOPE_AGENT);
    if ((old & 15) == 15)
      __hip_atomic_fetch_add(gb + 32, 1, __ATOMIC_RELEASE, __HIP_MEMORY_SCOPE_AGENT);
  }
}
__device__ __forceinline__ void g_wait(int* gb, int target) {
  if (threadIdx.x == 0) {
    while (__hip_atomic_load(gb + 32, __ATOMIC_RELAXED, __HIP_MEMORY_SCOPE_AGENT) < target)
      __builtin_amdgcn_s_sleep(1);
  }
  __builtin_amdgcn_fence(__ATOMIC_ACQUIRE, "workgroup");
  __syncthreads();
}

__global__ __launch_bounds__(NTHR, 2) void gru_seq_kernel(
    const float* __restrict__ input, const float* __restrict__ Wih1,
    const float* __restrict__ Whh1, const float* __restrict__ bih1, const float* __restrict__ bhh1,
    const float* __restrict__ Wih2, const float* __restrict__ Whh2,
    const float* __restrict__ bih2, const float* __restrict__ bhh2,
    const float* __restrict__ Wlin, const float* __restrict__ blinp,
    float* __restrict__ dout, u16* __restrict__ wsp, float* __restrict__ outsc,
    int* __restrict__ bar) {
  __shared__ __align__(16) char smem[150016];
  const int wg = blockIdx.x, tid = threadIdx.x;
  const int lane = tid & 63, wv = tid >> 6;
  const int l15 = lane & 15, l4 = lane >> 4;
  const int rt = wv & 3, kp = wv >> 2;     // 4 M-tiles x 2 k-split halves

  u16* Wh1h = wsp;           u16* Wh1l = wsp + WPL;
  u16* Wi2h = wsp + 2 * WPL; u16* Wi2l = wsp + 3 * WPL;
  u16* Wh2h = wsp + 4 * WPL; u16* Wh2l = wsp + 5 * WPL;
  u16* hb_  = wsp + 6 * WPL;
  u16* h1h = hb_;            u16* h1l = hb_ + 2 * HPL;   // [2][HPL] each
  u16* h2h = hb_ + 4 * HPL;  u16* h2l = hb_ + 6 * HPL;
  int* ibar = bar + 2048;

  // ---- init: split weights into bf16 hi/lo planes ----
  for (int i = wg * NTHR + tid; i < 3 * WPL; i += NBLK * NTHR) {
    int m = i / WPL, r = i - m * WPL;
    const float* src = (m == 0) ? Whh1 : (m == 1) ? Wih2 : Whh2;
    u16* dh = (m == 0) ? Wh1h : (m == 1) ? Wi2h : Wh2h;
    u16* dl = (m == 0) ? Wh1l : (m == 1) ? Wi2l : Wh2l;
    float v = src[r];
    u16 hbv = f2bf(v);
    dh[r] = hbv; dl[r] = f2bf(v - bf2f(hbv));
  }
  __syncthreads();
  if (tid == 0) {
    int old = __hip_atomic_fetch_add(ibar, 1, __ATOMIC_RELEASE, __HIP_MEMORY_SCOPE_AGENT);
    if (old == NBLK - 1)
      __hip_atomic_fetch_add(ibar + 32, 1, __ATOMIC_RELEASE, __HIP_MEMORY_SCOPE_AGENT);
  }

  // ---- block decomposition: xcd = wg&7 hosts col-slabs {2x,2x+1} ----
  const int xm = wg >> 3;
  const int cb = (wg & 7) * 2 + (xm & 1);   // 0..15 column-block (32 hcols)
  const int rb = xm >> 1;                   // 0..15 row-block (64 batch rows)
  int* gb1 = bar + rb * 128;
  int* gb2 = bar + rb * 128 + 64;
  const float blin = blinp[0];

  // ---- per-col constant table in LDS: [32 cols][5 f32x4] ----
  if (tid < 32) {
    int j0 = cb * 32 + tid;
    float* cc = (float*)(smem + CCOFF) + tid * 20;
    cc[0] = Wih1[j0]; cc[1] = Wih1[j0 + 512]; cc[2] = Wih1[j0 + 1024]; cc[3] = Wlin[j0];
    cc[4] = bih1[j0]; cc[5] = bih1[j0 + 512]; cc[6] = bih1[j0 + 1024]; cc[7] = 0.f;
    cc[8] = bhh1[j0]; cc[9] = bhh1[j0 + 512]; cc[10] = bhh1[j0 + 1024]; cc[11] = 0.f;
    cc[12] = bih2[j0]; cc[13] = bih2[j0 + 512]; cc[14] = bih2[j0 + 1024]; cc[15] = 0.f;
    cc[16] = bhh2[j0]; cc[17] = bhh2[j0 + 512]; cc[18] = bhh2[j0 + 1024]; cc[19] = 0.f;
  }

  // ---- weight staging slot decode (pre-swizzled source, linear LDS dst) ----
  const u16* wptrA[6]; u32 wdstA[6];
#pragma unroll
  for (int i = 0; i < 6; ++i) {
    u32 off = (u32)(wv * 6 + i) * 1024 + (u32)lane * 16;
    u32 pb = off / 12288, rem = off - pb * 12288;
    u32 r96 = rem >> 7, kb = rem & 127;
    u32 kbs = kb ^ ((r96 & 7) << 4);
    u32 g = r96 >> 5, r = r96 & 31;
    u32 eoff = (g * 512 + (u32)cb * 32 + r) * 512 + (kbs >> 1);
    const u16* base = (pb == 0) ? Wi2h : (pb == 1) ? Wh1h : (pb == 2) ? Wi2l : Wh1l;
    wptrA[i] = base + eoff;
    wdstA[i] = (u32)(wv * 6 + i) * 1024;
  }
  const u16* wptrH[3]; u32 wdstH[3];
#pragma unroll
  for (int i = 0; i < 3; ++i) {
    u32 off = (u32)(wv * 3 + i) * 1024 + (u32)lane * 16;
    u32 pb = off / 12288, rem = off - pb * 12288;
    u32 r96 = rem >> 7, kb = rem & 127;
    u32 kbs = kb ^ ((r96 & 7) << 4);
    u32 g = r96 >> 5, r = r96 & 31;
    u32 eoff = (g * 512 + (u32)cb * 32 + r) * 512 + (kbs >> 1);
    wptrH[i] = (pb ? Wh2l : Wh2h) + eoff;
    wdstH[i] = (u32)(wv * 3 + i) * 1024;
  }

  // ---- B-fragment LDS read offsets: tile v = g*2 + n16 ----
  u32 rowb[6];
#pragma unroll
  for (int g = 0; g < 3; ++g)
#pragma unroll
    for (int n16 = 0; n16 < 2; ++n16)
      rowb[g * 2 + n16] = (u32)(g * 32 + n16 * 16 + l15) * 128 +
                          (((u32)(kp * 64 + l4 * 16)) ^ ((u32)(l15 & 7) << 4));

  // ---- A-fragment global offset (direct-to-reg, no LDS) ----
  const u32 arow = (u32)(rb * 64 + rt * 16 + l15) * 512 + (u32)(kp * 32 + l4 * 8);

  const f32x4 vzero = {0.f, 0.f, 0.f, 0.f};
  f32x4 accn[6] = {vzero, vzero, vzero, vzero, vzero, vzero};  // gh1(t) partial, persists
  float h1s[2][4] = {}, h2s[2][4] = {};

  if (tid == 0) {
    while (__hip_atomic_load(ibar + 32, __ATOMIC_RELAXED, __HIP_MEMORY_SCOPE_AGENT) < 1)
      __builtin_amdgcn_s_sleep(1);
  }
  __builtin_amdgcn_fence(__ATOMIC_ACQUIRE, "workgroup");
  __syncthreads();

#define GA_ISSUE(c) do { char* d_ = smem + GA_P(((c) & 1)); \
    _Pragma("unroll") for (int i_ = 0; i_ < 6; ++i_) \
      gload16(wptrA[i_] + (c) * 64, d_ + wdstA[i_]); } while (0)
#define GH_ISSUE(c) do { char* d_ = smem + GH_P(((c) & 1)); \
    _Pragma("unroll") for (int i_ = 0; i_ < 3; ++i_) \
      gload16(wptrH[i_] + (c) * 64, d_ + wdstH[i_]); } while (0)

#define GA_CHUNK(p, AH, AL) do { const char* B_ = smem + GA_P(p); \
    _Pragma("unroll") for (int v_ = 0; v_ < 6; ++v_) { \
      bf16x8 bih = *(const bf16x8*)(B_ + rowb[v_]); \
      bf16x8 buh = *(const bf16x8*)(B_ + 12288 + rowb[v_]); \
      bf16x8 bil = *(const bf16x8*)(B_ + 24576 + rowb[v_]); \
      bf16x8 bul = *(const bf16x8*)(B_ + 36864 + rowb[v_]); \
      acci[v_] = MFMA(AH, bih, acci[v_]); \
      acci[v_] = MFMA(AL, bih, acci[v_]); \
      acci[v_] = MFMA(AH, bil, acci[v_]); \
      accn[v_] = MFMA(AH, buh, accn[v_]); \
      accn[v_] = MFMA(AL, buh, accn[v_]); \
      accn[v_] = MFMA(AH, bul, accn[v_]); } } while (0)

#define GH_CHUNK(p, AH, AL) do { const char* B_ = smem + GH_P(p); \
    _Pragma("unroll") for (int v_ = 0; v_ < 6; ++v_) { \
      bf16x8 bh = *(const bf16x8*)(B_ + rowb[v_]); \
      bf16x8 bl = *(const bf16x8*)(B_ + 12288 + rowb[v_]); \
      acch[v_] = MFMA(AH, bh, acch[v_]); \
      acch[v_] = MFMA(AL, bh, acch[v_]); \
      acch[v_] = MFMA(AH, bl, acch[v_]); } } while (0)

  for (int t = 0; t < TSTEPS; ++t) {
    const int cur = t & 1, prv = cur ^ 1;

    // teacher-forced input prefetch (read-only, safe before the wait)
    float xpre[4];
    if (t < WUP) {
#pragma unroll
      for (int rr = 0; rr < 4; ++rr)
        xpre[rr] = input[(rb * 64 + rt * 16 + l4 * 4 + rr) * 1024 + t];
    }

    if (t > 0) g_wait(gb2, t);   // h2(t-1), out(t-1) published

    if (t >= WUP) {
#pragma unroll
      for (int rr = 0; rr < 4; ++rr) {
        int b = rb * 64 + rt * 16 + l4 * 4 + rr;
        xpre[rr] = __hip_atomic_load(outsc + prv * 1024 + b, __ATOMIC_RELAXED,
                                     __HIP_MEMORY_SCOPE_AGENT) + blin;
      }
    }
    if (cb == 0 && tid < 64) {
      int b = rb * 64 + tid;
      if (t > 0) {
        float osc = __hip_atomic_load(outsc + prv * 1024 + b, __ATOMIC_RELAXED,
                                      __HIP_MEMORY_SCOPE_AGENT);
        dout[b * 1024 + (t - 1)] = osc + blin;
      }
      outsc[cur * 1024 + b] = 0.f;
    }

    // ---- EW1: k-split reduce of accn (=gh1(t)), then h1(t) on kp0 lanes ----
    if (kp == 1) {
#pragma unroll
      for (int v = 0; v < 6; ++v)
        *(f32x4*)(smem + REDOFF + v * 4096 + (rt * 64 + lane) * 16) = accn[v];
    }
    __syncthreads();
    if (kp == 0) {
      f32x4 a1f[6];
#pragma unroll
      for (int v = 0; v < 6; ++v)
        a1f[v] = accn[v] + *(const f32x4*)(smem + REDOFF + v * 4096 + (rt * 64 + lane) * 16);
      u16* h1hc = h1h + cur * HPL;
      u16* h1lc = h1l + cur * HPL;
#pragma unroll
      for (int n16 = 0; n16 < 2; ++n16) {
        const char* ccb = smem + CCOFF + (n16 * 16 + l15) * 80;
        f32x4 C0 = *(const f32x4*)ccb;
        f32x4 C1 = *(const f32x4*)(ccb + 16);
        f32x4 C2 = *(const f32x4*)(ccb + 32);
        int jj = cb * 32 + n16 * 16 + l15;
#pragma unroll
        for (int rr = 0; rr < 4; ++rr) {
          int b = rb * 64 + rt * 16 + l4 * 4 + rr;
          float x = xpre[rr];
          float r = sigm(fmaf(x, C0.x, C1.x) + a1f[n16][rr] + C2.x);
          float z = sigm(fmaf(x, C0.y, C1.y) + a1f[2 + n16][rr] + C2.y);
          float n = tanh_(fmaf(r, a1f[4 + n16][rr] + C2.z, fmaf(x, C0.z, C1.z)));
          float h = (1.f - z) * n + z * h1s[n16][rr];
          h1s[n16][rr] = h;
          u16 hbv = f2bf(h);
          int idx = b * 512 + jj;
          h1hc[idx] = hbv; h1lc[idx] = f2bf(h - bf2f(hbv));
        }
      }
    }
    g_arrive(gb1);   // publish h1(t): syncthreads drains EW1 stores; release wbl2

    // ---- GH: gh2 = h2(t-1)@Whh2^T — A direct from global, B streamed to LDS ----
    f32x4 acch[6] = {vzero, vzero, vzero, vzero, vzero, vzero};
    if (t > 0) {
      GH_ISSUE(0);
      const u16* pAh2 = h2h + prv * HPL + arow;
      const u16* pAl2 = h2l + prv * HPL + arow;
      i32x4 rA[16];
#pragma unroll
      for (int c = 0; c < 8; ++c) {
        rA[2 * c] = load_sc(pAh2 + c * 64);
        rA[2 * c + 1] = load_sc(pAl2 + c * 64);
      }
#pragma unroll
      for (int c = 0; c < 8; ++c) {
        if (c == 0) { asm volatile("s_waitcnt vmcnt(14)" ::: "memory"); }
        else       { asm volatile("s_waitcnt vmcnt(0)" ::: "memory"); }
        __builtin_amdgcn_s_barrier();
        __builtin_amdgcn_sched_barrier(0);
        if (c < 7) GH_ISSUE(c + 1);
        bf16x8 ah = __builtin_bit_cast(bf16x8, rA[2 * c]);
        bf16x8 al = __builtin_bit_cast(bf16x8, rA[2 * c + 1]);
        GH_CHUNK(c & 1, ah, al);
      }
    }
    g_wait(gb1, t + 1);

    // ---- GA: gi2(t) + gh1(t+1) from h1(t) ----
    f32x4 acci[6] = {vzero, vzero, vzero, vzero, vzero, vzero};
#pragma unroll
    for (int v = 0; v < 6; ++v) accn[v] = vzero;
    {
      GA_ISSUE(0);
      const u16* pAh = h1h + cur * HPL + arow;
      const u16* pAl = h1l + cur * HPL + arow;
      i32x4 rA[16];
#pragma unroll
      for (int c = 0; c < 8; ++c) {
        rA[2 * c] = load_sc(pAh + c * 64);
        rA[2 * c + 1] = load_sc(pAl + c * 64);
      }
#pragma unroll
      for (int c = 0; c < 8; ++c) {
        if (c == 0) { asm volatile("s_waitcnt vmcnt(14)" ::: "memory"); }
        else       { asm volatile("s_waitcnt vmcnt(0)" ::: "memory"); }
        __builtin_amdgcn_s_barrier();
        __builtin_amdgcn_sched_barrier(0);
        if (c < 7) GA_ISSUE(c + 1);
        bf16x8 ah = __builtin_bit_cast(bf16x8, rA[2 * c]);
        bf16x8 al = __builtin_bit_cast(bf16x8, rA[2 * c + 1]);
        GA_CHUNK(c & 1, ah, al);
      }
    }

    // ---- EW2: k-split reduce of acci/acch, h2(t) + output matvec on kp0 ----
    if (kp == 1) {
#pragma unroll
      for (int v = 0; v < 6; ++v) {
        *(f32x4*)(smem + REDOFF + v * 4096 + (rt * 64 + lane) * 16) = acci[v];
        *(f32x4*)(smem + REDOFF + 24576 + v * 4096 + (rt * 64 + lane) * 16) = acch[v];
      }
    }
    __syncthreads();
    if (kp == 0) {
      f32x4 a2i[6], a2h[6];
#pragma unroll
      for (int v = 0; v < 6; ++v) {
        a2i[v] = acci[v] + *(const f32x4*)(smem + REDOFF + v * 4096 + (rt * 64 + lane) * 16);
        a2h[v] = acch[v] + *(const f32x4*)(smem + REDOFF + 24576 + v * 4096 + (rt * 64 + lane) * 16);
      }
      u16* h2hc = h2h + cur * HPL;
      u16* h2lc = h2l + cur * HPL;
      float vsum[4] = {0.f, 0.f, 0.f, 0.f};
#pragma unroll
      for (int n16 = 0; n16 < 2; ++n16) {
        const char* ccb = smem + CCOFF + (n16 * 16 + l15) * 80;
        f32x4 C0 = *(const f32x4*)ccb;
        f32x4 C3 = *(const f32x4*)(ccb + 48);
        f32x4 C4 = *(const f32x4*)(ccb + 64);
        int jj = cb * 32 + n16 * 16 + l15;
#pragma unroll
        for (int rr = 0; rr < 4; ++rr) {
          int b = rb * 64 + rt * 16 + l4 * 4 + rr;
          float r = sigm(a2i[n16][rr] + C3.x + a2h[n16][rr] + C4.x);
          float z = sigm(a2i[2 + n16][rr] + C3.y + a2h[2 + n16][rr] + C4.y);
          float n = tanh_(fmaf(r, a2h[4 + n16][rr] + C4.z, a2i[4 + n16][rr] + C3.z));
          float h = (1.f - z) * n + z * h2s[n16][rr];
          h2s[n16][rr] = h;
          u16 hbv = f2bf(h);
          int idx = b * 512 + jj;
          h2hc[idx] = hbv; h2lc[idx] = f2bf(h - bf2f(hbv));
          vsum[rr] = fmaf(h, C0.w, vsum[rr]);
        }
      }
#pragma unroll
      for (int rr = 0; rr < 4; ++rr) {
        float v = vsum[rr];
        v += __shfl_xor(v, 1);
        v += __shfl_xor(v, 2);
        v += __shfl_xor(v, 4);
        v += __shfl_xor(v, 8);
        if (l15 == 0) {
          int b = rb * 64 + rt * 16 + l4 * 4 + rr;
          atomicAdd(outsc + cur * 1024 + b, v);
        }
      }
    }
    g_arrive(gb2);   // publish h2(t) + out(t)
  }

  g_wait(gb2, TSTEPS);
  if (cb == 0 && tid < 64) {
    int b = rb * 64 + tid;
    float osc = __hip_atomic_load(outsc + 1024 + b, __ATOMIC_RELAXED,
                                  __HIP_MEMORY_SCOPE_AGENT);
    dout[b * 1024 + 1023] = osc + blin;
  }
}

extern "C" void kernel_launch(void* const* d_in, const int* in_sizes, int n_in,
                              void* d_out, int out_size, void* d_ws, size_t ws_size,
                              hipStream_t stream) {
  (void)in_sizes; (void)n_in; (void)out_size; (void)ws_size;
  const float* input = (const float*)d_in[0];
  const float* Wih1  = (const float*)d_in[1];
  const float* Whh1  = (const float*)d_in[2];
  const float* bih1  = (const float*)d_in[3];
  const float* bhh1  = (const float*)d_in[4];
  const float* Wih2  = (const float*)d_in[5];
  const float* Whh2  = (const float*)d_in[6];
  const float* bih2  = (const float*)d_in[7];
  const float* bhh2  = (const float*)d_in[8];
  const float* Wlin  = (const float*)d_in[9];
  const float* blin  = (const float*)d_in[10];

  u16* wsp = (u16*)d_ws;
  size_t u16_count = (size_t)6 * WPL + (size_t)8 * HPL;
  float* outsc = (float*)((char*)d_ws + u16_count * 2);
  int* bar = (int*)((char*)outsc + 2048 * sizeof(float));

  hipMemsetAsync(bar, 0, 3 * 1024 * sizeof(int), stream);
  gru_seq_kernel<<<NBLK, NTHR, 0, stream>>>(input, Wih1, Whh1, bih1, bhh1,
                                            Wih2, Whh2, bih2, bhh2, Wlin, blin,
                                            (float*)d_out, wsp, outsc, bar);
}

// Round 7
// 46549.930 us; speedup vs baseline: 1.2911x; 1.2911x over previous
//
#include <hip/hip_runtime.h>

#define NBLK 256
#define NTHR 256
#define TSTEPS 1024
#define WUP 512
#define WPL 786432   /* weight plane elems: 1536*512 */
#define HPL 524288   /* u32 elems per h buffer: 1024*512 */

#define GA_LP(p) ((p) * 49152)            /* GA weight dbuf [0, 98304) */
#define GH_LP(p) (98304 + (p) * 24576)    /* GH weight dbuf [98304, 147456) */
#define CCOFF 147456                      /* per-col constants */
#define SMEMSZ 149504

typedef unsigned short u16;
typedef unsigned int u32;
typedef __bf16 bf16x8 __attribute__((ext_vector_type(8)));
typedef float f32x4 __attribute__((ext_vector_type(4)));
typedef int i32x4 __attribute__((ext_vector_type(4)));
typedef u32 u32x4 __attribute__((ext_vector_type(4)));

typedef __attribute__((address_space(3))) void as3v;
typedef __attribute__((address_space(1))) const void as1cv;

__device__ __forceinline__ void gload16(const u16* g, char* l) {
  __builtin_amdgcn_global_load_lds((as1cv*)g, (as3v*)l, 16, 0, 0);
}
// L1/L2-bypass coherent 16B ops: all cross-block data goes through L3 point.
__device__ __forceinline__ i32x4 load_sc(const u32* p) {
  i32x4 r;
  asm volatile("global_load_dwordx4 %0, %1, off sc0 sc1" : "=v"(r) : "v"(p) : "memory");
  return r;
}
__device__ __forceinline__ void store_sc(u32* p, i32x4 v) {
  asm volatile("global_store_dwordx4 %0, %1, off sc0 sc1" : : "v"(p), "v"(v) : "memory");
}
__device__ __forceinline__ u16 f2bf(float f) {
  u32 u = __float_as_uint(f);
  u += 0x7fffu + ((u >> 16) & 1u);
  return (u16)(u >> 16);
}
__device__ __forceinline__ float bf2f(u16 s) { return __uint_as_float(((u32)s) << 16); }
__device__ __forceinline__ float sigm(float v) { return 1.f / (1.f + __expf(-v)); }
__device__ __forceinline__ float tanh_(float v) {
  float e = __expf(2.f * v);
  return 1.f - 2.f / (e + 1.f);
}
__device__ __forceinline__ f32x4 MFMA(bf16x8 a, bf16x8 b, f32x4 c) {
  return __builtin_amdgcn_mfma_f32_16x16x32_bf16(a, b, c, 0, 0, 0);
}
// unpack 8 packed (hi<<16|lo) words -> hi-plane bf16x8 + lo-plane bf16x8
__device__ __forceinline__ void unpk(i32x4 a, i32x4 b, bf16x8& hi, bf16x8& lo) {
  u32x4 h, l;
  h[0] = __builtin_amdgcn_perm((u32)a[1], (u32)a[0], 0x07060302u);
  h[1] = __builtin_amdgcn_perm((u32)a[3], (u32)a[2], 0x07060302u);
  h[2] = __builtin_amdgcn_perm((u32)b[1], (u32)b[0], 0x07060302u);
  h[3] = __builtin_amdgcn_perm((u32)b[3], (u32)b[2], 0x07060302u);
  l[0] = __builtin_amdgcn_perm((u32)a[1], (u32)a[0], 0x05040100u);
  l[1] = __builtin_amdgcn_perm((u32)a[3], (u32)a[2], 0x05040100u);
  l[2] = __builtin_amdgcn_perm((u32)b[1], (u32)b[0], 0x05040100u);
  l[3] = __builtin_amdgcn_perm((u32)b[3], (u32)b[2], 0x05040100u);
  hi = __builtin_bit_cast(bf16x8, h);
  lo = __builtin_bit_cast(bf16x8, l);
}

// ---- write-through group barrier: NO release, NO wbl2, NO inv in hot loop ----
__device__ __forceinline__ void g_arrive(int* gb) {
  asm volatile("s_waitcnt vmcnt(0) lgkmcnt(0)" ::: "memory");  // sc stores at L3
  __builtin_amdgcn_s_barrier();
  if (threadIdx.x == 0) {
    int old = __hip_atomic_fetch_add(gb, 1, __ATOMIC_RELAXED, __HIP_MEMORY_SCOPE_AGENT);
    if ((old & 15) == 15)
      __hip_atomic_fetch_add(gb + 32, 1, __ATOMIC_RELAXED, __HIP_MEMORY_SCOPE_AGENT);
  }
}
__device__ __forceinline__ void g_wait(int* gb, int target) {
  if (threadIdx.x == 0) {
    while (__hip_atomic_load(gb + 32, __ATOMIC_RELAXED, __HIP_MEMORY_SCOPE_AGENT) < target)
      __builtin_amdgcn_s_sleep(1);
  }
  asm volatile("s_waitcnt lgkmcnt(0)" ::: "memory");
  __builtin_amdgcn_s_barrier();
  __builtin_amdgcn_sched_barrier(0);
}

__global__ __launch_bounds__(NTHR, 1) void gru_seq_kernel(
    const float* __restrict__ input, const float* __restrict__ Wih1,
    const float* __restrict__ Whh1, const float* __restrict__ bih1, const float* __restrict__ bhh1,
    const float* __restrict__ Wih2, const float* __restrict__ Whh2,
    const float* __restrict__ bih2, const float* __restrict__ bhh2,
    const float* __restrict__ Wlin, const float* __restrict__ blinp,
    float* __restrict__ dout, u16* __restrict__ wsp, float* __restrict__ outsc,
    int* __restrict__ bar) {
  __shared__ __align__(16) char smem[SMEMSZ];
  const int wg = blockIdx.x, tid = threadIdx.x;
  const int lane = tid & 63, wv = tid >> 6;
  const int l15 = lane & 15, l4 = lane >> 4;
  const int mf = wv >> 1, kp = wv & 1;      // 2 M-halves x 2 k-window-parities

  u16* Wh1h = wsp;           u16* Wh1l = wsp + WPL;
  u16* Wi2h = wsp + 2 * WPL; u16* Wi2l = wsp + 3 * WPL;
  u16* Wh2h = wsp + 4 * WPL; u16* Wh2l = wsp + 5 * WPL;
  u32* h1c = (u32*)(wsp + 6 * (size_t)WPL);  // packed hi|lo, [2][HPL]
  u32* h2c = h1c + 2 * HPL;
  int* ibar = bar + 2048;

  // ---- one-time init: split weights into bf16 hi/lo planes ----
  for (int i = wg * NTHR + tid; i < 3 * WPL; i += NBLK * NTHR) {
    int m = i / WPL, r = i - m * WPL;
    const float* src = (m == 0) ? Whh1 : (m == 1) ? Wih2 : Whh2;
    u16* dh = (m == 0) ? Wh1h : (m == 1) ? Wi2h : Wh2h;
    u16* dl = (m == 0) ? Wh1l : (m == 1) ? Wi2l : Wh2l;
    float v = src[r];
    u16 hbv = f2bf(v);
    dh[r] = hbv; dl[r] = f2bf(v - bf2f(hbv));
  }
  __syncthreads();
  if (tid == 0) {   // the ONE release we keep: pushes dirty weight lines to L3
    int old = __hip_atomic_fetch_add(ibar, 1, __ATOMIC_RELEASE, __HIP_MEMORY_SCOPE_AGENT);
    if (old == NBLK - 1)
      __hip_atomic_fetch_add(ibar + 32, 1, __ATOMIC_RELEASE, __HIP_MEMORY_SCOPE_AGENT);
  }

  // ---- block decomposition: xcd = wg&7 hosts col-slabs {2x,2x+1} ----
  const int xm = wg >> 3;
  const int cb = (wg & 7) * 2 + (xm & 1);
  const int rb = xm >> 1;
  int* gb1 = bar + rb * 128;
  int* gb2 = bar + rb * 128 + 64;
  const float blin = blinp[0];

  // ---- per-col constants in LDS: [14 planes][32 cols] ----
  if (tid < 32) {
    int j0 = cb * 32 + tid;
    float* cc = (float*)(smem + CCOFF);
    cc[0 * 32 + tid] = Wih1[j0];  cc[1 * 32 + tid] = Wih1[j0 + 512];
    cc[2 * 32 + tid] = Wih1[j0 + 1024];
    cc[3 * 32 + tid] = bih1[j0];  cc[4 * 32 + tid] = bih1[j0 + 512];
    cc[5 * 32 + tid] = bih1[j0 + 1024];
    cc[6 * 32 + tid] = bhh1[j0];  cc[7 * 32 + tid] = bhh1[j0 + 512];
    cc[8 * 32 + tid] = bhh1[j0 + 1024];
    cc[9 * 32 + tid] = bih2[j0] + bhh2[j0];
    cc[10 * 32 + tid] = bih2[j0 + 512] + bhh2[j0 + 512];
    cc[11 * 32 + tid] = bih2[j0 + 1024];
    cc[12 * 32 + tid] = bhh2[j0 + 1024];
    cc[13 * 32 + tid] = Wlin[j0];
  }

  // ---- weight gload slot decode (pre-swizzled source, linear LDS dst) ----
  const u16* wsrcA[12]; u32 wdstA_[12];
#pragma unroll
  for (int i = 0; i < 12; ++i) {
    u32 off = (u32)i * 4096 + (u32)tid * 16;
    u32 pl = off >= 24576 ? 1u : 0u; u32 rem = off - pl * 24576;
    u32 brow = rem >> 7, kb = rem & 127;
    u32 kbs = kb ^ ((brow & 7) << 4);
    u32 mat = brow >= 96 ? 1u : 0u; u32 s = brow - mat * 96;
    u32 g = s >> 5, r = s & 31;
    const u16* base = mat ? (pl ? Wh1l : Wh1h) : (pl ? Wi2l : Wi2h);
    wsrcA[i] = base + (g * 512 + (u32)cb * 32 + r) * 512 + (kbs >> 1);
    wdstA_[i] = off;
  }
  const u16* wsrcH[6]; u32 wdstH_[6];
#pragma unroll
  for (int i = 0; i < 6; ++i) {
    u32 off = (u32)i * 4096 + (u32)tid * 16;
    u32 pl = off >= 12288 ? 1u : 0u; u32 rem = off - pl * 12288;
    u32 brow = rem >> 7, kb = rem & 127;
    u32 kbs = kb ^ ((brow & 7) << 4);
    u32 g = brow >> 5, r = brow & 31;
    wsrcH[i] = (pl ? Wh2l : Wh2h) + (g * 512 + (u32)cb * 32 + r) * 512 + (kbs >> 1);
    wdstH_[i] = off;
  }

  // ---- B-fragment LDS read offsets (swizzled) ----
  u32 rowBA[12], rowBH[6];
#pragma unroll
  for (int nt = 0; nt < 12; ++nt) {
    u32 row = (u32)(nt / 6) * 96 + (u32)((nt % 6) >> 1) * 32 + (u32)(nt & 1) * 16 + (u32)l15;
    rowBA[nt] = row * 128 + (((u32)kp * 64 + (u32)l4 * 16) ^ ((row & 7) << 4));
  }
#pragma unroll
  for (int nt = 0; nt < 6; ++nt) {
    u32 row = (u32)(nt >> 1) * 32 + (u32)(nt & 1) * 16 + (u32)l15;
    rowBH[nt] = row * 128 + (((u32)kp * 64 + (u32)l4 * 16) ^ ((row & 7) << 4));
  }

  // ---- A (h) direct-to-reg base offset (u32 units) ----
  const u32 aoff_ = ((u32)(rb * 64 + mf * 32 + l15)) * 512 + (u32)kp * 32 + (u32)l4 * 4;

  // ---- EW thread mapping ----
  const int r_ = tid >> 2, cg = tid & 3;
  const int n16 = cg >> 1, colb8 = (cg & 1) * 8;

  const f32x4 vzero = {0.f, 0.f, 0.f, 0.f};
  f32x4 acci[12], accn[12], acch[12];
#pragma unroll
  for (int v = 0; v < 12; ++v) accn[v] = vzero;
  float h1s[8] = {}, h2s[8] = {};
  i32x4 aB[3][4];

  if (tid == 0) {
    while (__hip_atomic_load(ibar + 32, __ATOMIC_RELAXED, __HIP_MEMORY_SCOPE_AGENT) < 1)
      __builtin_amdgcn_s_sleep(1);
  }
  __syncthreads();

#define WISSUE_A(c, P) do { char* d_ = smem + GA_LP(P); \
    _Pragma("unroll") for (int i_ = 0; i_ < 12; ++i_) \
      gload16(wsrcA[i_] + (c) * 64, d_ + wdstA_[i_]); } while (0)
#define WISSUE_H(c, P) do { char* d_ = smem + GH_LP(P); \
    _Pragma("unroll") for (int i_ = 0; i_ < 6; ++i_) \
      gload16(wsrcH[i_] + (c) * 64, d_ + wdstH_[i_]); } while (0)
#define LOADA(dst, bp, c) do { \
    dst[0] = load_sc((bp) + (c) * 64); \
    dst[1] = load_sc((bp) + (c) * 64 + 16); \
    dst[2] = load_sc((bp) + (c) * 64 + 8192); \
    dst[3] = load_sc((bp) + (c) * 64 + 8192 + 16); } while (0)

#define GA_CHUNK(P, A) do { \
    bf16x8 ah0, al0, ah1, al1; \
    unpk(A[0], A[1], ah0, al0); unpk(A[2], A[3], ah1, al1); \
    const char* B_ = smem + GA_LP(P); \
    _Pragma("unroll") for (int nt = 0; nt < 12; ++nt) { \
      bf16x8 bh = *(const bf16x8*)(B_ + rowBA[nt]); \
      bf16x8 bl = *(const bf16x8*)(B_ + 24576 + rowBA[nt]); \
      f32x4* ac = (nt < 6) ? &acci[nt * 2] : &accn[(nt - 6) * 2]; \
      ac[0] = MFMA(ah0, bh, ac[0]); ac[0] = MFMA(al0, bh, ac[0]); ac[0] = MFMA(ah0, bl, ac[0]); \
      ac[1] = MFMA(ah1, bh, ac[1]); ac[1] = MFMA(al1, bh, ac[1]); ac[1] = MFMA(ah1, bl, ac[1]); \
    } } while (0)

#define GH_CHUNK(P, A) do { \
    bf16x8 ah0, al0, ah1, al1; \
    unpk(A[0], A[1], ah0, al0); unpk(A[2], A[3], ah1, al1); \
    const char* B_ = smem + GH_LP(P); \
    _Pragma("unroll") for (int nt = 0; nt < 6; ++nt) { \
      bf16x8 bh = *(const bf16x8*)(B_ + rowBH[nt]); \
      bf16x8 bl = *(const bf16x8*)(B_ + 12288 + rowBH[nt]); \
      f32x4* ac = &acch[nt * 2]; \
      ac[0] = MFMA(ah0, bh, ac[0]); ac[0] = MFMA(al0, bh, ac[0]); ac[0] = MFMA(ah0, bl, ac[0]); \
      ac[1] = MFMA(ah1, bh, ac[1]); ac[1] = MFMA(al1, bh, ac[1]); ac[1] = MFMA(ah1, bl, ac[1]); \
    } } while (0)

  for (int t = 0; t < TSTEPS; ++t) {
    const int cur = t & 1, prv = cur ^ 1;
    const u32 curH = (u32)cur * HPL, prvH = (u32)prv * HPL;

    float x = 0.f;
    if (t < WUP) x = input[(rb * 64 + r_) * 1024 + t];   // read-only prefetch

    if (t > 0) g_wait(gb2, t);

    // pre-issue GH inputs: h2(t-1) chunks 0,1 to regs + Whh2 chunk0 to LDS
    const u32* pA2 = h2c + prvH + aoff_;
    if (t > 0) {
      WISSUE_H(0, 0);
      LOADA(aB[0], pA2, 0);
      LOADA(aB[1], pA2, 1);
    }
    if (t >= WUP)
      x = __hip_atomic_load(outsc + prv * 1024 + rb * 64 + r_, __ATOMIC_RELAXED,
                            __HIP_MEMORY_SCOPE_AGENT) + blin;
    if (cb == 0 && tid < 64) {
      int b = rb * 64 + tid;
      if (t > 0) {
        float osc = __hip_atomic_load(outsc + prv * 1024 + b, __ATOMIC_RELAXED,
                                      __HIP_MEMORY_SCOPE_AGENT);
        dout[b * 1024 + (t - 1)] = osc + blin;
      }
      __hip_atomic_store(outsc + cur * 1024 + b, 0.f, __ATOMIC_RELAXED,
                         __HIP_MEMORY_SCOPE_AGENT);
    }

    // ---- EW1: k-exchange accn (=gh1(t)) via LDS, compute h1(t), store packed ----
    {
      float* red = (float*)smem;
#pragma unroll
      for (int v = 0; v < 6; ++v)
#pragma unroll
        for (int f = 0; f < 2; ++f) {
          float* w = red + ((u32)((v * 2 + kp) * 64 + mf * 32 + f * 16 + l4 * 4)) * 20 + l15;
          f32x4 a = accn[v * 2 + f];
          w[0] = a[0]; w[20] = a[1]; w[40] = a[2]; w[60] = a[3];
        }
      asm volatile("s_waitcnt lgkmcnt(0)" ::: "memory");
      __builtin_amdgcn_s_barrier();
      __builtin_amdgcn_sched_barrier(0);
      f32x4 gh[3][2];
#pragma unroll
      for (int g = 0; g < 3; ++g) {
        const float* p0 = red + ((u32)(((g * 2 + n16) * 2 + 0) * 64 + r_)) * 20 + colb8;
        const float* p1 = red + ((u32)(((g * 2 + n16) * 2 + 1) * 64 + r_)) * 20 + colb8;
        gh[g][0] = *(const f32x4*)p0 + *(const f32x4*)p1;
        gh[g][1] = *(const f32x4*)(p0 + 4) + *(const f32x4*)(p1 + 4);
      }
      const float* cc = (const float*)(smem + CCOFF);
      const int jb = cg * 8;
      f32x4 cP[9][2];
#pragma unroll
      for (int p = 0; p < 9; ++p) {
        cP[p][0] = *(const f32x4*)(cc + p * 32 + jb);
        cP[p][1] = *(const f32x4*)(cc + p * 32 + jb + 4);
      }
      u32 pk[8];
#pragma unroll
      for (int i = 0; i < 8; ++i) {
        const int q = i >> 2, e = i & 3;
        float rg = sigm(fmaf(x, cP[0][q][e], cP[3][q][e]) + gh[0][q][e] + cP[6][q][e]);
        float zg = sigm(fmaf(x, cP[1][q][e], cP[4][q][e]) + gh[1][q][e] + cP[7][q][e]);
        float ng = tanh_(fmaf(rg, gh[2][q][e] + cP[8][q][e], fmaf(x, cP[2][q][e], cP[5][q][e])));
        float h = (1.f - zg) * ng + zg * h1s[i];
        h1s[i] = h;
        u16 hb_ = f2bf(h);
        pk[i] = ((u32)hb_ << 16) | (u32)f2bf(h - bf2f(hb_));
      }
      u32* dst = h1c + curH + (u32)(rb * 64 + r_) * 512 + (u32)cb * 32 + cg * 4;
      i32x4 s0, s1;
      s0[0] = (int)pk[0]; s0[1] = (int)pk[1]; s0[2] = (int)pk[2]; s0[3] = (int)pk[3];
      s1[0] = (int)pk[4]; s1[1] = (int)pk[5]; s1[2] = (int)pk[6]; s1[3] = (int)pk[7];
      store_sc(dst, s0); store_sc(dst + 16, s1);
    }
    g_arrive(gb1);     // drains h1 stores to L3, then relaxed flag

    WISSUE_A(0, 0);    // GA weight chunk0 streams during GH (GA region free now)

    // ---- GH: gh2 = h2(t-1) @ Whh2^T ----
#pragma unroll
    for (int v = 0; v < 12; ++v) acch[v] = vzero;
    if (t > 0) {
#pragma unroll
      for (int c = 0; c < 8; ++c) {
        if (c == 0)     { asm volatile("s_waitcnt vmcnt(12)" ::: "memory"); }
        else if (c < 7) { asm volatile("s_waitcnt vmcnt(4)" ::: "memory"); }
        else            { asm volatile("s_waitcnt vmcnt(0)" ::: "memory"); }
        __builtin_amdgcn_s_barrier();
        __builtin_amdgcn_sched_barrier(0);
        if (c < 7) WISSUE_H(c + 1, (c + 1) & 1);
        if (c < 6) LOADA(aB[(c + 2) % 3], pA2, c + 2);
        GH_CHUNK(c & 1, aB[c % 3]);
      }
    }
    g_wait(gb1, t + 1);

    // ---- GA: gi2(t) + gh1(t+1) from h1(t) ----
    const u32* pA1 = h1c + curH + aoff_;
    LOADA(aB[0], pA1, 0);
    LOADA(aB[1], pA1, 1);
#pragma unroll
    for (int v = 0; v < 12; ++v) { acci[v] = vzero; accn[v] = vzero; }
#pragma unroll
    for (int c = 0; c < 8; ++c) {
      if (c < 7) { asm volatile("s_waitcnt vmcnt(4)" ::: "memory"); }
      else       { asm volatile("s_waitcnt vmcnt(0)" ::: "memory"); }
      __builtin_amdgcn_s_barrier();
      __builtin_amdgcn_sched_barrier(0);
      if (c < 7) WISSUE_A(c + 1, (c + 1) & 1);
      if (c < 6) LOADA(aB[(c + 2) % 3], pA1, c + 2);
      GA_CHUNK(c & 1, aB[c % 3]);
    }
    asm volatile("s_waitcnt lgkmcnt(0)" ::: "memory");
    __builtin_amdgcn_s_barrier();   // GA bufs dead -> RED2 safe
    __builtin_amdgcn_sched_barrier(0);

    // ---- EW2: exchange {r-sum, z-sum, i_n, h_n}, compute h2(t) + out ----
    {
      float* red = (float*)smem;
#pragma unroll
      for (int n6 = 0; n6 < 2; ++n6)
#pragma unroll
        for (int f = 0; f < 2; ++f) {
          const u32 row = (u32)(mf * 32 + f * 16 + l4 * 4);
          f32x4 rs = acci[(0 + n6) * 2 + f] + acch[(0 + n6) * 2 + f];
          f32x4 zs = acci[(2 + n6) * 2 + f] + acch[(2 + n6) * 2 + f];
          f32x4 iv = acci[(4 + n6) * 2 + f];
          f32x4 hv = acch[(4 + n6) * 2 + f];
          float* w0 = red + ((u32)(((0 + n6) * 2 + kp) * 64) + row) * 20 + l15;
          float* w1 = red + ((u32)(((2 + n6) * 2 + kp) * 64) + row) * 20 + l15;
          float* w2 = red + ((u32)(((4 + n6) * 2 + kp) * 64) + row) * 20 + l15;
          float* w3 = red + ((u32)(((6 + n6) * 2 + kp) * 64) + row) * 20 + l15;
          w0[0] = rs[0]; w0[20] = rs[1]; w0[40] = rs[2]; w0[60] = rs[3];
          w1[0] = zs[0]; w1[20] = zs[1]; w1[40] = zs[2]; w1[60] = zs[3];
          w2[0] = iv[0]; w2[20] = iv[1]; w2[40] = iv[2]; w2[60] = iv[3];
          w3[0] = hv[0]; w3[20] = hv[1]; w3[40] = hv[2]; w3[60] = hv[3];
        }
      asm volatile("s_waitcnt lgkmcnt(0)" ::: "memory");
      __builtin_amdgcn_s_barrier();
      __builtin_amdgcn_sched_barrier(0);
      f32x4 S[4][2];
#pragma unroll
      for (int k = 0; k < 4; ++k) {
        const float* p0 = red + ((u32)(((k * 2 + n16) * 2 + 0) * 64 + r_)) * 20 + colb8;
        const float* p1 = red + ((u32)(((k * 2 + n16) * 2 + 1) * 64 + r_)) * 20 + colb8;
        S[k][0] = *(const f32x4*)p0 + *(const f32x4*)p1;
        S[k][1] = *(const f32x4*)(p0 + 4) + *(const f32x4*)(p1 + 4);
      }
      const float* cc = (const float*)(smem + CCOFF);
      const int jb = cg * 8;
      f32x4 cQ[5][2];
#pragma unroll
      for (int p = 0; p < 5; ++p) {
        cQ[p][0] = *(const f32x4*)(cc + (9 + p) * 32 + jb);
        cQ[p][1] = *(const f32x4*)(cc + (9 + p) * 32 + jb + 4);
      }
      u32 pk[8];
      float vsum = 0.f;
#pragma unroll
      for (int i = 0; i < 8; ++i) {
        const int q = i >> 2, e = i & 3;
        float rg = sigm(S[0][q][e] + cQ[0][q][e]);
        float zg = sigm(S[1][q][e] + cQ[1][q][e]);
        float ng = tanh_(S[2][q][e] + cQ[2][q][e] + rg * (S[3][q][e] + cQ[3][q][e]));
        float h = (1.f - zg) * ng + zg * h2s[i];
        h2s[i] = h;
        u16 hb_ = f2bf(h);
        pk[i] = ((u32)hb_ << 16) | (u32)f2bf(h - bf2f(hb_));
        vsum = fmaf(h, cQ[4][q][e], vsum);
      }
      u32* dst = h2c + curH + (u32)(rb * 64 + r_) * 512 + (u32)cb * 32 + cg * 4;
      i32x4 s0, s1;
      s0[0] = (int)pk[0]; s0[1] = (int)pk[1]; s0[2] = (int)pk[2]; s0[3] = (int)pk[3];
      s1[0] = (int)pk[4]; s1[1] = (int)pk[5]; s1[2] = (int)pk[6]; s1[3] = (int)pk[7];
      store_sc(dst, s0); store_sc(dst + 16, s1);
      vsum += __shfl_xor(vsum, 1);
      vsum += __shfl_xor(vsum, 2);
      if (cg == 0) atomicAdd(outsc + cur * 1024 + rb * 64 + r_, vsum);
    }
    g_arrive(gb2);
  }

  g_wait(gb2, TSTEPS);
  if (cb == 0 && tid < 64) {
    int b = rb * 64 + tid;
    float osc = __hip_atomic_load(outsc + 1024 + b, __ATOMIC_RELAXED,
                                  __HIP_MEMORY_SCOPE_AGENT);
    dout[b * 1024 + 1023] = osc + blin;
  }
}

extern "C" void kernel_launch(void* const* d_in, const int* in_sizes, int n_in,
                              void* d_out, int out_size, void* d_ws, size_t ws_size,
                              hipStream_t stream) {
  (void)in_sizes; (void)n_in; (void)out_size; (void)ws_size;
  const float* input = (const float*)d_in[0];
  const float* Wih1  = (const float*)d_in[1];
  const float* Whh1  = (const float*)d_in[2];
  const float* bih1  = (const float*)d_in[3];
  const float* bhh1  = (const float*)d_in[4];
  const float* Wih2  = (const float*)d_in[5];
  const float* Whh2  = (const float*)d_in[6];
  const float* bih2  = (const float*)d_in[7];
  const float* bhh2  = (const float*)d_in[8];
  const float* Wlin  = (const float*)d_in[9];
  const float* blin  = (const float*)d_in[10];

  u16* wsp = (u16*)d_ws;
  u32* hC = (u32*)(wsp + 6 * (size_t)WPL);
  float* outsc = (float*)(hC + 4 * (size_t)HPL);
  int* bar = (int*)(outsc + 2048);

  hipMemsetAsync(bar, 0, 16384, stream);
  gru_seq_kernel<<<NBLK, NTHR, 0, stream>>>(input, Wih1, Whh1, bih1, bhh1,
                                            Wih2, Whh2, bih2, bhh2, Wlin, blin,
                                            (float*)d_out, wsp, outsc, bar);
}